// Round 1
// baseline (211.210 us; speedup 1.0000x reference)
//
#include <hip/hip_runtime.h>
#include <math.h>

#define C_CH 256
#define GG 49
#define ROW_ELEMS (C_CH * GG)        // 12544
#define ROW_VEC4  (ROW_ELEMS / 4)    // 3136
#define NP 32
#define NREAL 512

__global__ __launch_bounds__(256) void gate_fused_kernel(
    const float* __restrict__ x,
    const float* __restrict__ prev_x,
    const float* __restrict__ match,
    const float* __restrict__ proj_w,
    const float* __restrict__ proj_b,
    const float* __restrict__ ln_g,
    const float* __restrict__ ln_b,
    const float* __restrict__ w1,
    const float* __restrict__ b1,
    const float* __restrict__ w2,
    const float* __restrict__ b2,
    float* __restrict__ out)
{
    const int m   = blockIdx.x;   // 0..511
    const int tid = threadIdx.x;  // 0..255

    __shared__ __align__(16) float tile[ROW_ELEMS];   // 49 KB staging
    __shared__ double pooled[C_CH];
    __shared__ double parts[8][NP];
    __shared__ double vecs[2][NP];                    // [0]=curr, [1]=prev (normalized)
    __shared__ int    s_top1;
    __shared__ double s_wmass[4], s_went[4];
    __shared__ float  s_wm1[4], s_wm2[4];
    __shared__ int    s_wi1[4];

    // ---------------- phase 1: match-row statistics ----------------
    const float* __restrict__ row = match + (size_t)m * (NREAL + 1);
    float v0 = row[tid];
    float v1 = row[tid + 256];

    double mass = (double)v0 + (double)v1;
    double r0 = fmax((double)v0, 1e-9);
    double r1 = fmax((double)v1, 1e-9);
    double entn = r0 * log(r0) + r1 * log(r1);  // note: feat[3] = -ent = sum(r*log r)

    float m1, m2; int i1;
    if (v0 >= v1) { m1 = v0; m2 = v1; i1 = tid; }        // ties -> lower index
    else          { m1 = v1; m2 = v0; i1 = tid + 256; }

    #pragma unroll
    for (int mask = 1; mask < 64; mask <<= 1) {
        double o_mass = __shfl_xor(mass, mask, 64);
        double o_ent  = __shfl_xor(entn, mask, 64);
        float  o_m1   = __shfl_xor(m1,   mask, 64);
        float  o_m2   = __shfl_xor(m2,   mask, 64);
        int    o_i1   = __shfl_xor(i1,   mask, 64);
        mass += o_mass; entn += o_ent;
        if (o_m1 > m1)      { m2 = fmaxf(m1, o_m2); m1 = o_m1; i1 = o_i1; }
        else if (o_m1 < m1) { m2 = fmaxf(m2, o_m1); }
        else                { m2 = m1; i1 = (o_i1 < i1) ? o_i1 : i1; } // duplicate max
    }

    const int wid = tid >> 6, lane = tid & 63;
    if (lane == 0) {
        s_wmass[wid] = mass; s_went[wid] = entn;
        s_wm1[wid] = m1; s_wm2[wid] = m2; s_wi1[wid] = i1;
    }
    __syncthreads();
    if (tid == 0) {
        double tmass = s_wmass[0], tent = s_went[0];
        float tm1 = s_wm1[0], tm2 = s_wm2[0]; int ti1 = s_wi1[0];
        for (int w = 1; w < 4; ++w) {
            tmass += s_wmass[w]; tent += s_went[w];
            float om1 = s_wm1[w], om2 = s_wm2[w]; int oi1 = s_wi1[w];
            if (om1 > tm1)      { tm2 = fmaxf(tm1, om2); tm1 = om1; ti1 = oi1; }
            else if (om1 < tm1) { tm2 = fmaxf(tm2, om1); }
            else                { tm2 = tm1; ti1 = (oi1 < ti1) ? oi1 : ti1; }
        }
        s_wmass[0] = tmass; s_went[0] = tent; s_wm1[0] = tm1; s_wm2[0] = tm2;
        s_top1 = (tmass > 1e-9) ? ti1 : 0;   // has_real ? argmax : 0
    }
    __syncthreads();
    const int top1 = s_top1;

    // ------- phase 2: pool + project + LN + l2norm (x row, then prev[top1]) -------
    for (int phase = 0; phase < 2; ++phase) {
        const float* __restrict__ src =
            (phase == 0) ? (x + (size_t)m * ROW_ELEMS)
                         : (prev_x + (size_t)top1 * ROW_ELEMS);
        const float4* __restrict__ s4 = reinterpret_cast<const float4*>(src);
        float4* t4 = reinterpret_cast<float4*>(tile);
        for (int i = tid; i < ROW_VEC4; i += 256) t4[i] = s4[i];
        __syncthreads();

        {   // per-channel mean over 49 (stride-49 LDS reads: odd stride, conflict-free)
            const float* p = &tile[tid * GG];
            double s = 0.0;
            #pragma unroll
            for (int j = 0; j < GG; ++j) s += (double)p[j];
            pooled[tid] = s * (1.0 / 49.0);
        }
        __syncthreads();

        {   // projection: 8 channel-groups x 32 outputs
            const int p = tid & 31, g = tid >> 5;
            const float* __restrict__ wrow = proj_w + p * C_CH + g * 32;
            const double* pl = pooled + g * 32;
            double acc = 0.0;
            #pragma unroll
            for (int c = 0; c < 32; ++c) acc += pl[c] * (double)wrow[c];
            parts[g][p] = acc;
        }
        __syncthreads();

        if (tid < NP) {
            double v = (double)proj_b[tid];
            #pragma unroll
            for (int g = 0; g < 8; ++g) v += parts[g][tid];
            // LayerNorm over 32 lanes (lanes 0..31 of wave 0)
            double s = v;
            #pragma unroll
            for (int mask = 1; mask <= 16; mask <<= 1) s += __shfl_xor(s, mask, 64);
            double mu = s * (1.0 / 32.0);
            double d  = v - mu;
            double q  = d * d;
            #pragma unroll
            for (int mask = 1; mask <= 16; mask <<= 1) q += __shfl_xor(q, mask, 64);
            double var = q * (1.0 / 32.0);
            double y = (double)ln_g[tid] * (d / sqrt(var + 1e-5)) + (double)ln_b[tid];
            // l2 normalize
            double yy = y * y;
            #pragma unroll
            for (int mask = 1; mask <= 16; mask <<= 1) yy += __shfl_xor(yy, mask, 64);
            double n = fmax(sqrt(yy), 1e-12);
            vecs[phase][tid] = y / n;
        }
        __syncthreads();
    }

    // ---------------- phase 3: features + MLP + sigmoid ----------------
    if (tid == 0) {
        double tmass = s_wmass[0];
        double feat3 = s_went[0];                  // -ent
        float  pm  = s_wm1[0], pm2 = s_wm2[0];
        bool has_real = tmass > 1e-9;

        double cs = 0.0;
        if (has_real) {
            double s = 0.0;
            #pragma unroll
            for (int p = 0; p < NP; ++p) s += vecs[0][p] * vecs[1][p];
            cs = s;
        }
        double p_dummy = (double)row[NREAL];
        double feat[5] = {1.0 - p_dummy, (double)pm, (double)pm - (double)pm2, feat3, cs};

        double logit = (double)b2[0];
        for (int h = 0; h < 32; ++h) {
            double a = (double)b1[h];
            #pragma unroll
            for (int f = 0; f < 5; ++f) a += feat[f] * (double)w1[h * 5 + f];
            if (a > 0.0) logit += a * (double)w2[h];
        }
        double c = 1.0 / (1.0 + exp(-logit));
        if (!(tmass > 1e-6)) c = 0.0;             // no_real mask (before clip)
        c = fmin(fmax(c, 0.001), 0.999);
        out[m] = (float)c;
    }
}

extern "C" void kernel_launch(void* const* d_in, const int* in_sizes, int n_in,
                              void* d_out, int out_size, void* d_ws, size_t ws_size,
                              hipStream_t stream) {
    (void)in_sizes; (void)n_in; (void)d_ws; (void)ws_size; (void)out_size;
    const float* x      = (const float*)d_in[0];
    const float* prev_x = (const float*)d_in[1];
    const float* match  = (const float*)d_in[2];
    const float* proj_w = (const float*)d_in[3];
    const float* proj_b = (const float*)d_in[4];
    const float* ln_g   = (const float*)d_in[5];
    const float* ln_b   = (const float*)d_in[6];
    const float* w1     = (const float*)d_in[7];
    const float* b1     = (const float*)d_in[8];
    const float* w2     = (const float*)d_in[9];
    const float* b2     = (const float*)d_in[10];
    float* out = (float*)d_out;

    gate_fused_kernel<<<dim3(512), dim3(256), 0, stream>>>(
        x, prev_x, match, proj_w, proj_b, ln_g, ln_b, w1, b1, w2, b2, out);
}